// Round 8
// baseline (244.573 us; speedup 1.0000x reference)
//
#include <hip/hip_runtime.h>
#include <hip/hip_bf16.h>

#define N_USERS   100000
#define EMBED_DIM 128
#define N_EDGES   640000
#define ZERO_ROW  N_USERS          // embb row of zeros for padded edge slots

typedef __bf16 bf16x8 __attribute__((ext_vector_type(8)));
typedef float  f32x4  __attribute__((ext_vector_type(4)));

// ---- workspace layout (bytes) ----
// [0,          25,600,256)  embb   bf16 [100001][128] (row 100000 = zeros)
// [25,600,256, 26,000,256)  counts int  [100000]
// [26,000,256, 26,000,260)  total  int  [1]   (memset together with counts)
// [26,000,384, 26,400,384)  start  int  [100000]  (padded CSR starts, 4-aligned)
// [26,400,384, 26,800,384)  cursor int  [100000]
// [26,800,384, 30,560,384)  perm   int  [940000 max] (src ids grouped by dst,
//                                                     padded to x4 with ZERO_ROW)
// [30,560,384, 30,593,152)  wlb    bf16 [128][128]
// [30,593,152, 30,625,920)  wrb    bf16 [128][128]
// [30,625,920, 56,225,920)  aggb   bf16 [100000][128]
#define OFF_COUNTS 25600256
#define OFF_TOTAL  26000256
#define OFF_START  26000384
#define OFF_CURSOR 26400384
#define OFF_PERM   26800384
#define OFF_WLB    30560384
#define OFF_WRB    30593152
#define OFF_AGGB   30625920

__device__ __forceinline__ unsigned short f2bf_rne(float f) {
    union { float f; unsigned u; } c; c.f = f;
    unsigned u = c.u + 0x7fffu + ((c.u >> 16) & 1u);
    return (unsigned short)(u >> 16);
}
__device__ __forceinline__ float bf2f_lo(unsigned u) {
    union { float f; unsigned u; } c; c.u = u << 16;
    return c.f;
}
__device__ __forceinline__ float bf2f_hi(unsigned u) {
    union { float f; unsigned u; } c; c.u = u & 0xffff0000u;
    return c.f;
}

// Convert W_l/W_r -> bf16, emb -> embb (bf16), zero-row, dst histogram.
// counts/total pre-zeroed by hipMemsetAsync (stream-ordered before us).
// grid: 6250 x 256
__global__ __launch_bounds__(256) void k_init(const float* __restrict__ emb,
                                              const float* __restrict__ Wl,
                                              const float* __restrict__ Wr,
                                              const int* __restrict__ dst,
                                              unsigned short* __restrict__ embb,
                                              int* __restrict__ counts,
                                              unsigned short* __restrict__ wlb,
                                              unsigned short* __restrict__ wrb) {
    int i = blockIdx.x * 256 + threadIdx.x;
    if (i < 4096) {    // 16384 floats per W matrix / 4
        float4 a = ((const float4*)Wl)[i];
        float4 b = ((const float4*)Wr)[i];
        int o = i * 4;
        wlb[o+0] = f2bf_rne(a.x); wlb[o+1] = f2bf_rne(a.y);
        wlb[o+2] = f2bf_rne(a.z); wlb[o+3] = f2bf_rne(a.w);
        wrb[o+0] = f2bf_rne(b.x); wrb[o+1] = f2bf_rne(b.y);
        wrb[o+2] = f2bf_rne(b.z); wrb[o+3] = f2bf_rne(b.w);
    }
    // zero row at index N_USERS: 128 bf16 = 256 B = exactly 16 int4.
    if (i < 16) {
        int4 z = {0, 0, 0, 0};
        ((int4*)(embb + (size_t)ZERO_ROW * EMBED_DIM))[i] = z;
    }
    // emb -> embb, 8 floats per thread
    float4 a = ((const float4*)emb)[i * 2 + 0];
    float4 b = ((const float4*)emb)[i * 2 + 1];
    int4 p;
    p.x = (int)f2bf_rne(a.x) | ((int)f2bf_rne(a.y) << 16);
    p.y = (int)f2bf_rne(a.z) | ((int)f2bf_rne(a.w) << 16);
    p.z = (int)f2bf_rne(b.x) | ((int)f2bf_rne(b.y) << 16);
    p.w = (int)f2bf_rne(b.z) | ((int)f2bf_rne(b.w) << 16);
    ((int4*)embb)[i] = p;
    // dst histogram (overlaps with the streaming conversion)
    if (i < N_EDGES) atomicAdd(&counts[dst[i]], 1);
}

// Exclusive allocation of contiguous per-node regions, PADDED to multiples
// of 4; fill pad slots of perm with ZERO_ROW.  grid: 98 x 256
__global__ __launch_bounds__(256) void k_alloc(const int* __restrict__ counts,
                                               int* __restrict__ start,
                                               int* __restrict__ cursor,
                                               int* __restrict__ total,
                                               int* __restrict__ perm) {
    int i    = blockIdx.x * 256 + threadIdx.x;
    int lane = threadIdx.x & 63;
    int wv   = threadIdx.x >> 6;
    int4 c4 = {0, 0, 0, 0};
    if (i < 25000) c4 = ((const int4*)counts)[i];
    int4 p4;                       // padded counts
    p4.x = (c4.x + 3) & ~3;
    p4.y = (c4.y + 3) & ~3;
    p4.z = (c4.z + 3) & ~3;
    p4.w = (c4.w + 3) & ~3;
    int csum = p4.x + p4.y + p4.z + p4.w;
    int pre = csum;
#pragma unroll
    for (int d = 1; d < 64; d <<= 1) {
        int v = __shfl_up(pre, d);
        if (lane >= d) pre += v;
    }
    __shared__ int swv[4];
    __shared__ int sgbase;
    if (lane == 63) swv[wv] = pre;
    __syncthreads();
    if (threadIdx.x == 0)
        sgbase = atomicAdd(total, swv[0] + swv[1] + swv[2] + swv[3]);
    __syncthreads();
    int waveoff = 0;
    for (int w = 0; w < wv; w++) waveoff += swv[w];
    int base = sgbase + waveoff + (pre - csum);
    if (i < 25000) {
        int4 s;
        s.x = base;
        s.y = s.x + p4.x;
        s.z = s.y + p4.y;
        s.w = s.z + p4.z;
        ((int4*)start)[i]  = s;
        ((int4*)cursor)[i] = s;
        // fill pad slots with ZERO_ROW
        for (int k = c4.x; k < p4.x; k++) perm[s.x + k] = ZERO_ROW;
        for (int k = c4.y; k < p4.y; k++) perm[s.y + k] = ZERO_ROW;
        for (int k = c4.z; k < p4.z; k++) perm[s.z + k] = ZERO_ROW;
        for (int k = c4.w; k < p4.w; k++) perm[s.w + k] = ZERO_ROW;
    }
}

// Scatter edge src-ids into dst-grouped buckets.  grid: 2500 x 256
__global__ __launch_bounds__(256) void k_perm(const int* __restrict__ src,
                                              const int* __restrict__ dst,
                                              int* __restrict__ cursor,
                                              int* __restrict__ perm) {
    int e = blockIdx.x * 256 + threadIdx.x;
    if (e < N_EDGES) {
        int pos = atomicAdd(&cursor[dst[e]], 1);
        perm[pos] = src[e];
    }
}

// Gather-side mean aggregation: one wave per 2 nodes (interleaved chains,
// 8 row-loads in flight), padded x4 edge lists (no serialized remainder),
// int4 perm loads, fp32 accumulate, pre-divide, store bf16.
// grid: 12500 x 256 (4 waves -> 8 nodes per block)
__global__ __launch_bounds__(256) void k_aggregate(const unsigned short* __restrict__ embb,
                                                   const int* __restrict__ start,
                                                   const int* __restrict__ counts,
                                                   const int* __restrict__ perm,
                                                   unsigned short* __restrict__ aggb) {
    int gw   = (blockIdx.x * 256 + threadIdx.x) >> 6;   // 0..49999
    int lane = threadIdx.x & 63;
    int nA = gw * 2;
    int nB = nA + 1;
    int sA = start[nA], cntA = counts[nA];
    int sB = start[nB], cntB = counts[nB];
    int ga = (cntA + 3) >> 2;      // padded groups of 4
    int gb = (cntB + 3) >> 2;
    int gmin = ga < gb ? ga : gb;
    float2 accA = {0.f, 0.f}, accB = {0.f, 0.f};
    const unsigned short* ep = embb;
    int off = lane * 2;

    int t = 0;
    for (; t < gmin; t++) {                 // 8 rows in flight
        int4 ia = ((const int4*)(perm + sA))[t];
        int4 ib = ((const int4*)(perm + sB))[t];
        unsigned a0 = *(const unsigned*)(ep + (size_t)ia.x * EMBED_DIM + off);
        unsigned a1 = *(const unsigned*)(ep + (size_t)ia.y * EMBED_DIM + off);
        unsigned a2 = *(const unsigned*)(ep + (size_t)ia.z * EMBED_DIM + off);
        unsigned a3 = *(const unsigned*)(ep + (size_t)ia.w * EMBED_DIM + off);
        unsigned b0 = *(const unsigned*)(ep + (size_t)ib.x * EMBED_DIM + off);
        unsigned b1 = *(const unsigned*)(ep + (size_t)ib.y * EMBED_DIM + off);
        unsigned b2 = *(const unsigned*)(ep + (size_t)ib.z * EMBED_DIM + off);
        unsigned b3 = *(const unsigned*)(ep + (size_t)ib.w * EMBED_DIM + off);
        accA.x += (bf2f_lo(a0) + bf2f_lo(a1)) + (bf2f_lo(a2) + bf2f_lo(a3));
        accA.y += (bf2f_hi(a0) + bf2f_hi(a1)) + (bf2f_hi(a2) + bf2f_hi(a3));
        accB.x += (bf2f_lo(b0) + bf2f_lo(b1)) + (bf2f_lo(b2) + bf2f_lo(b3));
        accB.y += (bf2f_hi(b0) + bf2f_hi(b1)) + (bf2f_hi(b2) + bf2f_hi(b3));
    }
    for (int ta = t; ta < ga; ta++) {
        int4 ia = ((const int4*)(perm + sA))[ta];
        unsigned a0 = *(const unsigned*)(ep + (size_t)ia.x * EMBED_DIM + off);
        unsigned a1 = *(const unsigned*)(ep + (size_t)ia.y * EMBED_DIM + off);
        unsigned a2 = *(const unsigned*)(ep + (size_t)ia.z * EMBED_DIM + off);
        unsigned a3 = *(const unsigned*)(ep + (size_t)ia.w * EMBED_DIM + off);
        accA.x += (bf2f_lo(a0) + bf2f_lo(a1)) + (bf2f_lo(a2) + bf2f_lo(a3));
        accA.y += (bf2f_hi(a0) + bf2f_hi(a1)) + (bf2f_hi(a2) + bf2f_hi(a3));
    }
    for (int tb = t; tb < gb; tb++) {
        int4 ib = ((const int4*)(perm + sB))[tb];
        unsigned b0 = *(const unsigned*)(ep + (size_t)ib.x * EMBED_DIM + off);
        unsigned b1 = *(const unsigned*)(ep + (size_t)ib.y * EMBED_DIM + off);
        unsigned b2 = *(const unsigned*)(ep + (size_t)ib.z * EMBED_DIM + off);
        unsigned b3 = *(const unsigned*)(ep + (size_t)ib.w * EMBED_DIM + off);
        accB.x += (bf2f_lo(b0) + bf2f_lo(b1)) + (bf2f_lo(b2) + bf2f_lo(b3));
        accB.y += (bf2f_hi(b0) + bf2f_hi(b1)) + (bf2f_hi(b2) + bf2f_hi(b3));
    }
    float invA = (cntA > 0) ? 1.0f / (float)cntA : 0.0f;
    float invB = (cntB > 0) ? 1.0f / (float)cntB : 0.0f;
    unsigned oA = (unsigned)f2bf_rne(accA.x * invA) | ((unsigned)f2bf_rne(accA.y * invA) << 16);
    unsigned oB = (unsigned)f2bf_rne(accB.x * invB) | ((unsigned)f2bf_rne(accB.y * invB) << 16);
    *(unsigned*)(aggb + (size_t)nA * EMBED_DIM + off) = oA;
    *(unsigned*)(aggb + (size_t)nB * EMBED_DIM + off) = oB;
}

// out[n][j] = sum_k aggb[n][k]*Wl[j][k] + embb[n][k]*Wr[j][k] + bl[j]
// ILP-restructured: 2 row-tiles per block; ALL A/E fragment loads for both
// tiles issue first (one latency exposure), then L2-hot weight loads, then
// MFMA.  Each wave owns 2 of 8 column-tiles.  grid: 3125 x 256
#define TILES_PER_BLOCK 2
__global__ __launch_bounds__(256, 3) void k_matmul(const unsigned short* __restrict__ aggb,
                                                   const unsigned short* __restrict__ wlb,
                                                   const unsigned short* __restrict__ wrb,
                                                   const unsigned short* __restrict__ embb,
                                                   const float* __restrict__ bl,
                                                   float* __restrict__ out) {
    int wave = threadIdx.x >> 6;
    int lane = threadIdx.x & 63;
    int quad = lane >> 4;      // 0..3
    int m    = lane & 15;
    int jt0  = wave * 2;       // this wave's two column tiles
    int tile0 = blockIdx.x * TILES_PER_BLOCK;

    // ---- 1) A/E fragment loads for BOTH tiles (HBM/L3 latency) ----
    bf16x8 af[TILES_PER_BLOCK][4], ef[TILES_PER_BLOCK][4];
#pragma unroll
    for (int t = 0; t < TILES_PER_BLOCK; t++) {
        int node = (tile0 + t) * 16 + m;
        const __bf16* arow = (const __bf16*)aggb + (size_t)node * EMBED_DIM;
        const __bf16* erow = (const __bf16*)embb + (size_t)node * EMBED_DIM;
#pragma unroll
        for (int kt = 0; kt < 4; kt++) {
            int kb = kt * 32 + quad * 8;
            af[t][kt] = *(const bf16x8*)(arow + kb);
            ef[t][kt] = *(const bf16x8*)(erow + kb);
        }
    }

    // ---- 2) weight fragments (64 KB tables, L2-hot) ----
    bf16x8 wl[2][4], wr[2][4];
#pragma unroll
    for (int jj = 0; jj < 2; jj++) {
#pragma unroll
        for (int kt = 0; kt < 4; kt++) {
            size_t off = (size_t)((jt0 + jj) * 16 + m) * EMBED_DIM + kt * 32 + quad * 8;
            wl[jj][kt] = *(const bf16x8*)((const __bf16*)wlb + off);
            wr[jj][kt] = *(const bf16x8*)((const __bf16*)wrb + off);
        }
    }
    float bias[2];
    bias[0] = bl[(jt0 + 0) * 16 + m];
    bias[1] = bl[(jt0 + 1) * 16 + m];

    // ---- 3) MFMA + store per tile ----
#pragma unroll
    for (int t = 0; t < TILES_PER_BLOCK; t++) {
        int row0 = (tile0 + t) * 16;
        f32x4 acc[2] = {{0.f,0.f,0.f,0.f}, {0.f,0.f,0.f,0.f}};
#pragma unroll
        for (int kt = 0; kt < 4; kt++) {
#pragma unroll
            for (int jj = 0; jj < 2; jj++) {
                acc[jj] = __builtin_amdgcn_mfma_f32_16x16x32_bf16(af[t][kt], wl[jj][kt], acc[jj], 0, 0, 0);
                acc[jj] = __builtin_amdgcn_mfma_f32_16x16x32_bf16(ef[t][kt], wr[jj][kt], acc[jj], 0, 0, 0);
            }
        }
        // C/D layout: col = lane&15, row = quad*4 + reg
#pragma unroll
        for (int jj = 0; jj < 2; jj++) {
#pragma unroll
            for (int r = 0; r < 4; r++) {
                int orow = row0 + quad * 4 + r;
                out[(size_t)orow * EMBED_DIM + (jt0 + jj) * 16 + m] = acc[jj][r] + bias[jj];
            }
        }
    }
}

extern "C" void kernel_launch(void* const* d_in, const int* in_sizes, int n_in,
                              void* d_out, int out_size, void* d_ws, size_t ws_size,
                              hipStream_t stream) {
    const float* emb = (const float*)d_in[0];
    const float* Wl  = (const float*)d_in[1];
    const float* bl  = (const float*)d_in[2];
    const float* Wr  = (const float*)d_in[3];
    const int*   src = (const int*)d_in[4];
    const int*   dst = (const int*)d_in[5];
    float* out = (float*)d_out;

    char* ws = (char*)d_ws;
    unsigned short* embb   = (unsigned short*)ws;
    int*            counts = (int*)(ws + OFF_COUNTS);
    int*            total  = (int*)(ws + OFF_TOTAL);
    int*            start  = (int*)(ws + OFF_START);
    int*            cursor = (int*)(ws + OFF_CURSOR);
    int*            perm   = (int*)(ws + OFF_PERM);
    unsigned short* wlb    = (unsigned short*)(ws + OFF_WLB);
    unsigned short* wrb    = (unsigned short*)(ws + OFF_WRB);
    unsigned short* aggb   = (unsigned short*)(ws + OFF_AGGB);

    // zero counts + total (graph-capturable memset node)
    hipMemsetAsync(ws + OFF_COUNTS, 0, (OFF_TOTAL - OFF_COUNTS) + 4, stream);

    k_init<<<6250, 256, 0, stream>>>(emb, Wl, Wr, dst, embb, counts, wlb, wrb);
    k_alloc<<<98, 256, 0, stream>>>(counts, start, cursor, total, perm);
    k_perm<<<2500, 256, 0, stream>>>(src, dst, cursor, perm);
    k_aggregate<<<12500, 256, 0, stream>>>(embb, start, counts, perm, aggb);
    k_matmul<<<3125, 256, 0, stream>>>(aggb, wlb, wrb, embb, bl, out);
}

// Round 9
// 213.143 us; speedup vs baseline: 1.1475x; 1.1475x over previous
//
#include <hip/hip_runtime.h>
#include <hip/hip_bf16.h>

#define N_USERS   100000
#define EMBED_DIM 128
#define N_EDGES   640000
#define ZERO_ROW  N_USERS          // embb row of zeros for padded edge slots

typedef __bf16 bf16x8 __attribute__((ext_vector_type(8)));
typedef float  f32x4  __attribute__((ext_vector_type(4)));

// ---- workspace layout (bytes) ----
// [0,          25,600,256)  embb   bf16 [100001][128] (row 100000 = zeros)
// [25,600,256, 26,000,256)  counts int  [100000]
// [26,000,256, 26,000,260)  total  int  [1]   (memset together with counts)
// [26,000,384, 26,400,384)  start  int  [100000]  (padded CSR starts, 4-aligned)
// [26,400,384, 26,800,384)  cursor int  [100000]
// [26,800,384, 30,560,384)  perm   int  [940000 max] (src ids grouped by dst,
//                                                     padded to x4 with ZERO_ROW)
// [30,560,384, 30,593,152)  wlsw   bf16 [16384]  Wl in MFMA-fragment order
// [30,593,152, 30,625,920)  wrsw   bf16 [16384]  Wr in MFMA-fragment order
// [30,625,920, 56,225,920)  aggb   bf16 [100000][128]
#define OFF_COUNTS 25600256
#define OFF_TOTAL  26000256
#define OFF_START  26000384
#define OFF_CURSOR 26400384
#define OFF_PERM   26800384
#define OFF_WLSW   30560384
#define OFF_WRSW   30593152
#define OFF_AGGB   30625920

__device__ __forceinline__ unsigned short f2bf_rne(float f) {
    union { float f; unsigned u; } c; c.f = f;
    unsigned u = c.u + 0x7fffu + ((c.u >> 16) & 1u);
    return (unsigned short)(u >> 16);
}
__device__ __forceinline__ float bf2f_lo(unsigned u) {
    union { float f; unsigned u; } c; c.u = u << 16;
    return c.f;
}
__device__ __forceinline__ float bf2f_hi(unsigned u) {
    union { float f; unsigned u; } c; c.u = u & 0xffff0000u;
    return c.f;
}

// Convert emb -> embb (bf16), zero-row, dst histogram, and write W_l/W_r in
// MFMA B-fragment order:  wsw[((jt*4+kt)*64 + lane)*8 + j]
//   = W[jt*16 + (lane&15)][kt*32 + (lane>>4)*8 + j]
// so a wave's fragment load in k_matmul is base + lane*16B (fully coalesced).
// counts/total pre-zeroed by hipMemsetAsync.  grid: 6250 x 256
__global__ __launch_bounds__(256) void k_init(const float* __restrict__ emb,
                                              const float* __restrict__ Wl,
                                              const float* __restrict__ Wr,
                                              const int* __restrict__ dst,
                                              unsigned short* __restrict__ embb,
                                              int* __restrict__ counts,
                                              unsigned short* __restrict__ wlsw,
                                              unsigned short* __restrict__ wrsw) {
    int i = blockIdx.x * 256 + threadIdx.x;
    if (i < 2048) {    // 2048 threads x 8 elems = 16384 = one W table
        int li = i & 63;            // lane
        int kt = (i >> 6) & 3;
        int jt = i >> 8;            // 0..7
        int row  = jt * 16 + (li & 15);
        int colb = kt * 32 + ((li >> 4) << 3);
        const float4* pl = (const float4*)(Wl + row * 128 + colb);
        const float4* pr = (const float4*)(Wr + row * 128 + colb);
        float4 l0 = pl[0], l1 = pl[1];
        float4 r0 = pr[0], r1 = pr[1];
        int o = i * 8;
        wlsw[o+0] = f2bf_rne(l0.x); wlsw[o+1] = f2bf_rne(l0.y);
        wlsw[o+2] = f2bf_rne(l0.z); wlsw[o+3] = f2bf_rne(l0.w);
        wlsw[o+4] = f2bf_rne(l1.x); wlsw[o+5] = f2bf_rne(l1.y);
        wlsw[o+6] = f2bf_rne(l1.z); wlsw[o+7] = f2bf_rne(l1.w);
        wrsw[o+0] = f2bf_rne(r0.x); wrsw[o+1] = f2bf_rne(r0.y);
        wrsw[o+2] = f2bf_rne(r0.z); wrsw[o+3] = f2bf_rne(r0.w);
        wrsw[o+4] = f2bf_rne(r1.x); wrsw[o+5] = f2bf_rne(r1.y);
        wrsw[o+6] = f2bf_rne(r1.z); wrsw[o+7] = f2bf_rne(r1.w);
    }
    // zero row at index N_USERS: 128 bf16 = 256 B = exactly 16 int4.
    if (i < 16) {
        int4 z = {0, 0, 0, 0};
        ((int4*)(embb + (size_t)ZERO_ROW * EMBED_DIM))[i] = z;
    }
    // emb -> embb, 8 floats per thread
    float4 a = ((const float4*)emb)[i * 2 + 0];
    float4 b = ((const float4*)emb)[i * 2 + 1];
    int4 p;
    p.x = (int)f2bf_rne(a.x) | ((int)f2bf_rne(a.y) << 16);
    p.y = (int)f2bf_rne(a.z) | ((int)f2bf_rne(a.w) << 16);
    p.z = (int)f2bf_rne(b.x) | ((int)f2bf_rne(b.y) << 16);
    p.w = (int)f2bf_rne(b.z) | ((int)f2bf_rne(b.w) << 16);
    ((int4*)embb)[i] = p;
    // dst histogram (overlaps with the streaming conversion)
    if (i < N_EDGES) atomicAdd(&counts[dst[i]], 1);
}

// Exclusive allocation of contiguous per-node regions, PADDED to multiples
// of 4; fill pad slots of perm with ZERO_ROW.  grid: 98 x 256
__global__ __launch_bounds__(256) void k_alloc(const int* __restrict__ counts,
                                               int* __restrict__ start,
                                               int* __restrict__ cursor,
                                               int* __restrict__ total,
                                               int* __restrict__ perm) {
    int i    = blockIdx.x * 256 + threadIdx.x;
    int lane = threadIdx.x & 63;
    int wv   = threadIdx.x >> 6;
    int4 c4 = {0, 0, 0, 0};
    if (i < 25000) c4 = ((const int4*)counts)[i];
    int4 p4;                       // padded counts
    p4.x = (c4.x + 3) & ~3;
    p4.y = (c4.y + 3) & ~3;
    p4.z = (c4.z + 3) & ~3;
    p4.w = (c4.w + 3) & ~3;
    int csum = p4.x + p4.y + p4.z + p4.w;
    int pre = csum;
#pragma unroll
    for (int d = 1; d < 64; d <<= 1) {
        int v = __shfl_up(pre, d);
        if (lane >= d) pre += v;
    }
    __shared__ int swv[4];
    __shared__ int sgbase;
    if (lane == 63) swv[wv] = pre;
    __syncthreads();
    if (threadIdx.x == 0)
        sgbase = atomicAdd(total, swv[0] + swv[1] + swv[2] + swv[3]);
    __syncthreads();
    int waveoff = 0;
    for (int w = 0; w < wv; w++) waveoff += swv[w];
    int base = sgbase + waveoff + (pre - csum);
    if (i < 25000) {
        int4 s;
        s.x = base;
        s.y = s.x + p4.x;
        s.z = s.y + p4.y;
        s.w = s.z + p4.z;
        ((int4*)start)[i]  = s;
        ((int4*)cursor)[i] = s;
        // fill pad slots with ZERO_ROW
        for (int k = c4.x; k < p4.x; k++) perm[s.x + k] = ZERO_ROW;
        for (int k = c4.y; k < p4.y; k++) perm[s.y + k] = ZERO_ROW;
        for (int k = c4.z; k < p4.z; k++) perm[s.z + k] = ZERO_ROW;
        for (int k = c4.w; k < p4.w; k++) perm[s.w + k] = ZERO_ROW;
    }
}

// Scatter edge src-ids into dst-grouped buckets.  grid: 2500 x 256
__global__ __launch_bounds__(256) void k_perm(const int* __restrict__ src,
                                              const int* __restrict__ dst,
                                              int* __restrict__ cursor,
                                              int* __restrict__ perm) {
    int e = blockIdx.x * 256 + threadIdx.x;
    if (e < N_EDGES) {
        int pos = atomicAdd(&cursor[dst[e]], 1);
        perm[pos] = src[e];
    }
}

// Gather-side mean aggregation: one wave per 2 nodes (interleaved chains,
// 8 row-loads in flight), padded x4 edge lists, int4 perm loads, fp32
// accumulate, pre-divide, store bf16.  grid: 12500 x 256
__global__ __launch_bounds__(256) void k_aggregate(const unsigned short* __restrict__ embb,
                                                   const int* __restrict__ start,
                                                   const int* __restrict__ counts,
                                                   const int* __restrict__ perm,
                                                   unsigned short* __restrict__ aggb) {
    int gw   = (blockIdx.x * 256 + threadIdx.x) >> 6;   // 0..49999
    int lane = threadIdx.x & 63;
    int nA = gw * 2;
    int nB = nA + 1;
    int sA = start[nA], cntA = counts[nA];
    int sB = start[nB], cntB = counts[nB];
    int ga = (cntA + 3) >> 2;      // padded groups of 4
    int gb = (cntB + 3) >> 2;
    int gmin = ga < gb ? ga : gb;
    float2 accA = {0.f, 0.f}, accB = {0.f, 0.f};
    const unsigned short* ep = embb;
    int off = lane * 2;

    int t = 0;
    for (; t < gmin; t++) {                 // 8 rows in flight
        int4 ia = ((const int4*)(perm + sA))[t];
        int4 ib = ((const int4*)(perm + sB))[t];
        unsigned a0 = *(const unsigned*)(ep + (size_t)ia.x * EMBED_DIM + off);
        unsigned a1 = *(const unsigned*)(ep + (size_t)ia.y * EMBED_DIM + off);
        unsigned a2 = *(const unsigned*)(ep + (size_t)ia.z * EMBED_DIM + off);
        unsigned a3 = *(const unsigned*)(ep + (size_t)ia.w * EMBED_DIM + off);
        unsigned b0 = *(const unsigned*)(ep + (size_t)ib.x * EMBED_DIM + off);
        unsigned b1 = *(const unsigned*)(ep + (size_t)ib.y * EMBED_DIM + off);
        unsigned b2 = *(const unsigned*)(ep + (size_t)ib.z * EMBED_DIM + off);
        unsigned b3 = *(const unsigned*)(ep + (size_t)ib.w * EMBED_DIM + off);
        accA.x += (bf2f_lo(a0) + bf2f_lo(a1)) + (bf2f_lo(a2) + bf2f_lo(a3));
        accA.y += (bf2f_hi(a0) + bf2f_hi(a1)) + (bf2f_hi(a2) + bf2f_hi(a3));
        accB.x += (bf2f_lo(b0) + bf2f_lo(b1)) + (bf2f_lo(b2) + bf2f_lo(b3));
        accB.y += (bf2f_hi(b0) + bf2f_hi(b1)) + (bf2f_hi(b2) + bf2f_hi(b3));
    }
    for (int ta = t; ta < ga; ta++) {
        int4 ia = ((const int4*)(perm + sA))[ta];
        unsigned a0 = *(const unsigned*)(ep + (size_t)ia.x * EMBED_DIM + off);
        unsigned a1 = *(const unsigned*)(ep + (size_t)ia.y * EMBED_DIM + off);
        unsigned a2 = *(const unsigned*)(ep + (size_t)ia.z * EMBED_DIM + off);
        unsigned a3 = *(const unsigned*)(ep + (size_t)ia.w * EMBED_DIM + off);
        accA.x += (bf2f_lo(a0) + bf2f_lo(a1)) + (bf2f_lo(a2) + bf2f_lo(a3));
        accA.y += (bf2f_hi(a0) + bf2f_hi(a1)) + (bf2f_hi(a2) + bf2f_hi(a3));
    }
    for (int tb = t; tb < gb; tb++) {
        int4 ib = ((const int4*)(perm + sB))[tb];
        unsigned b0 = *(const unsigned*)(ep + (size_t)ib.x * EMBED_DIM + off);
        unsigned b1 = *(const unsigned*)(ep + (size_t)ib.y * EMBED_DIM + off);
        unsigned b2 = *(const unsigned*)(ep + (size_t)ib.z * EMBED_DIM + off);
        unsigned b3 = *(const unsigned*)(ep + (size_t)ib.w * EMBED_DIM + off);
        accB.x += (bf2f_lo(b0) + bf2f_lo(b1)) + (bf2f_lo(b2) + bf2f_lo(b3));
        accB.y += (bf2f_hi(b0) + bf2f_hi(b1)) + (bf2f_hi(b2) + bf2f_hi(b3));
    }
    float invA = (cntA > 0) ? 1.0f / (float)cntA : 0.0f;
    float invB = (cntB > 0) ? 1.0f / (float)cntB : 0.0f;
    unsigned oA = (unsigned)f2bf_rne(accA.x * invA) | ((unsigned)f2bf_rne(accA.y * invA) << 16);
    unsigned oB = (unsigned)f2bf_rne(accB.x * invB) | ((unsigned)f2bf_rne(accB.y * invB) << 16);
    *(unsigned*)(aggb + (size_t)nA * EMBED_DIM + off) = oA;
    *(unsigned*)(aggb + (size_t)nB * EMBED_DIM + off) = oB;
}

// out[n][j] = sum_k aggb[n][k]*Wl[j][k] + embb[n][k]*Wr[j][k] + bl[j]
// Canonical LDS-staged tile: block = 32 rows x 128 cols, 4 waves.
//  - aggb/embb 32-row slabs staged via CONTIGUOUS global loads into padded
//    LDS (stride 136 shorts; balanced minimal banking for b128 frag reads)
//  - W fragments loaded from the PRE-SWIZZLED tables: base + lane*16B,
//    fully coalesced, L2-hot
// This removes the address-divergent 64B-segment loads that made rounds 2-8
// request-rate-bound (~4600 segments/block -> ~770).
// grid: 3125 x 256
#define LDS_S 136
__global__ __launch_bounds__(256) void k_matmul(const unsigned short* __restrict__ aggb,
                                                const unsigned short* __restrict__ wlsw,
                                                const unsigned short* __restrict__ wrsw,
                                                const unsigned short* __restrict__ embb,
                                                const float* __restrict__ bl,
                                                float* __restrict__ out) {
    __shared__ unsigned short sa[32 * LDS_S];
    __shared__ unsigned short se[32 * LDS_S];
    int tid  = threadIdx.x;
    int wave = tid >> 6;
    int lane = tid & 63;
    int quad = lane >> 4;      // 0..3
    int m    = lane & 15;
    int jt0  = wave * 2;       // this wave's two column tiles
    int node0 = blockIdx.x * 32;

    // ---- W fragments from swizzled tables: contiguous 1 KB per load ----
    bf16x8 wl[2][4], wr[2][4];
#pragma unroll
    for (int jj = 0; jj < 2; jj++) {
#pragma unroll
        for (int kt = 0; kt < 4; kt++) {
            size_t o = (size_t)((((jt0 + jj) * 4 + kt) * 64 + lane)) * 8;
            wl[jj][kt] = *(const bf16x8*)((const __bf16*)wlsw + o);
            wr[jj][kt] = *(const bf16x8*)((const __bf16*)wrsw + o);
        }
    }
    float bias[2];
    bias[0] = bl[(jt0 + 0) * 16 + m];
    bias[1] = bl[(jt0 + 1) * 16 + m];

    // ---- stage 32-row slabs of aggb/embb: contiguous 8 KB each ----
    const int4* aslab = (const int4*)(aggb + (size_t)node0 * EMBED_DIM);
    const int4* eslab = (const int4*)(embb + (size_t)node0 * EMBED_DIM);
#pragma unroll
    for (int p = 0; p < 2; p++) {
        int g   = p * 256 + tid;        // 512 chunks of 16 B = 8 KB
        int row = g >> 4;
        int c   = g & 15;
        int4 va = aslab[g];
        int4 ve = eslab[g];
        *(int4*)(sa + row * LDS_S + c * 8) = va;
        *(int4*)(se + row * LDS_S + c * 8) = ve;
    }
    __syncthreads();

    // ---- fragments from LDS + MFMA ----
    bf16x8 af[2][4], ef[2][4];
#pragma unroll
    for (int rt = 0; rt < 2; rt++) {
#pragma unroll
        for (int kt = 0; kt < 4; kt++) {
            int o = (rt * 16 + m) * LDS_S + kt * 32 + quad * 8;
            af[rt][kt] = *(const bf16x8*)(sa + o);
            ef[rt][kt] = *(const bf16x8*)(se + o);
        }
    }

#pragma unroll
    for (int rt = 0; rt < 2; rt++) {
        f32x4 acc[2] = {{0.f,0.f,0.f,0.f}, {0.f,0.f,0.f,0.f}};
#pragma unroll
        for (int kt = 0; kt < 4; kt++) {
#pragma unroll
            for (int jj = 0; jj < 2; jj++) {
                acc[jj] = __builtin_amdgcn_mfma_f32_16x16x32_bf16(af[rt][kt], wl[jj][kt], acc[jj], 0, 0, 0);
                acc[jj] = __builtin_amdgcn_mfma_f32_16x16x32_bf16(ef[rt][kt], wr[jj][kt], acc[jj], 0, 0, 0);
            }
        }
        // C/D layout: col = lane&15, row = quad*4 + reg
#pragma unroll
        for (int jj = 0; jj < 2; jj++) {
#pragma unroll
            for (int r = 0; r < 4; r++) {
                int orow = node0 + rt * 16 + quad * 4 + r;
                out[(size_t)orow * EMBED_DIM + (jt0 + jj) * 16 + m] = acc[jj][r] + bias[jj];
            }
        }
    }
}

extern "C" void kernel_launch(void* const* d_in, const int* in_sizes, int n_in,
                              void* d_out, int out_size, void* d_ws, size_t ws_size,
                              hipStream_t stream) {
    const float* emb = (const float*)d_in[0];
    const float* Wl  = (const float*)d_in[1];
    const float* bl  = (const float*)d_in[2];
    const float* Wr  = (const float*)d_in[3];
    const int*   src = (const int*)d_in[4];
    const int*   dst = (const int*)d_in[5];
    float* out = (float*)d_out;

    char* ws = (char*)d_ws;
    unsigned short* embb   = (unsigned short*)ws;
    int*            counts = (int*)(ws + OFF_COUNTS);
    int*            total  = (int*)(ws + OFF_TOTAL);
    int*            start  = (int*)(ws + OFF_START);
    int*            cursor = (int*)(ws + OFF_CURSOR);
    int*            perm   = (int*)(ws + OFF_PERM);
    unsigned short* wlsw   = (unsigned short*)(ws + OFF_WLSW);
    unsigned short* wrsw   = (unsigned short*)(ws + OFF_WRSW);
    unsigned short* aggb   = (unsigned short*)(ws + OFF_AGGB);

    // zero counts + total (graph-capturable memset node)
    hipMemsetAsync(ws + OFF_COUNTS, 0, (OFF_TOTAL - OFF_COUNTS) + 4, stream);

    k_init<<<6250, 256, 0, stream>>>(emb, Wl, Wr, dst, embb, counts, wlsw, wrsw);
    k_alloc<<<98, 256, 0, stream>>>(counts, start, cursor, total, perm);
    k_perm<<<2500, 256, 0, stream>>>(src, dst, cursor, perm);
    k_aggregate<<<12500, 256, 0, stream>>>(embb, start, counts, perm, aggb);
    k_matmul<<<3125, 256, 0, stream>>>(aggb, wlsw, wrsw, embb, bl, out);
}